// Round 19
// baseline (2149.942 us; speedup 1.0000x reference)
//
#include <hip/hip_runtime.h>
#include <cstdint>
#include <cstddef>

// Problem dims (fixed)
#define BB 2048
#define SS 256
#define HH 256
#define AA 2
#define TT 50
// Pipeline: 4 groups x 64 blocks (L0,L1,L2,L4), 32 rows/block, 512 thr
#define ROWS  32
#define NTHR  512
#define NLG   64
#define NGRID 256
#define KSTR  272            // wt: floats per k row (256 + 16 pad)
#define WLAYER (256 * KSTR)
#define LSTR  36             // in_lds row stride: 32 j + 4 pad
#define S3P   260            // s3_lds row stride (multiple of 4)

struct Params {
  const float* x;
  const float* fu[3]; const float* fv[3]; const float* fs[3];
  const float* f4u; const float* f4v; const float* f4s;
  const float* W[3]; const float* bs[3];
  const float* W4; const float* b4;
  float* out;
  float* wt3;        // [3][256 k][272] W transposed
  float* partials;   // [4 ch][2 par][6 st][64 g]
  unsigned* flags;   // [0..191] prod[hop][g], [256..447] ack[hop][g],
                     // [512..515] ctr[ch], [520] init
  uint8_t* sbuf;     // [3 hop][2 par][2048][256] spike bytes
  float* xT;         // [TT][BB*SS] (optional)
  int use_xt;
};

__device__ __forceinline__ void pstore(float* p, float v) {
  __hip_atomic_store(p, v, __ATOMIC_RELAXED, __HIP_MEMORY_SCOPE_AGENT);
}
__device__ __forceinline__ float pload(const float* p) {
  return __hip_atomic_load(p, __ATOMIC_RELAXED, __HIP_MEMORY_SCOPE_AGENT);
}
__device__ __forceinline__ void bstore(uint8_t* p, uint8_t v) {
  __hip_atomic_store(p, v, __ATOMIC_RELAXED, __HIP_MEMORY_SCOPE_AGENT);
}
__device__ __forceinline__ uint8_t bload(const uint8_t* p) {
  return __hip_atomic_load(p, __ATOMIC_RELAXED, __HIP_MEMORY_SCOPE_AGENT);
}
__device__ __forceinline__ unsigned uload_acq(const unsigned* p) {
  return __hip_atomic_load(p, __ATOMIC_ACQUIRE, __HIP_MEMORY_SCOPE_AGENT);
}
__device__ __forceinline__ void ustore_rel(unsigned* p, unsigned v) {
  __hip_atomic_store(p, v, __ATOMIC_RELEASE, __HIP_MEMORY_SCOPE_AGENT);
}
__device__ __forceinline__ void uadd(unsigned* p) {
  __hip_atomic_fetch_add(p, 1u, __ATOMIC_ACQ_REL, __HIP_MEMORY_SCOPE_AGENT);
}

// 16 FMAs: acc[jj][i] += IV[jj] * WV[i]
#define OUTER(IV, WV)                                        \
  acc[0][0] = fmaf((IV).x, (WV).x, acc[0][0]);               \
  acc[0][1] = fmaf((IV).x, (WV).y, acc[0][1]);               \
  acc[0][2] = fmaf((IV).x, (WV).z, acc[0][2]);               \
  acc[0][3] = fmaf((IV).x, (WV).w, acc[0][3]);               \
  acc[1][0] = fmaf((IV).y, (WV).x, acc[1][0]);               \
  acc[1][1] = fmaf((IV).y, (WV).y, acc[1][1]);               \
  acc[1][2] = fmaf((IV).y, (WV).z, acc[1][2]);               \
  acc[1][3] = fmaf((IV).y, (WV).w, acc[1][3]);               \
  acc[2][0] = fmaf((IV).z, (WV).x, acc[2][0]);               \
  acc[2][1] = fmaf((IV).z, (WV).y, acc[2][1]);               \
  acc[2][2] = fmaf((IV).z, (WV).z, acc[2][2]);               \
  acc[2][3] = fmaf((IV).z, (WV).w, acc[2][3]);               \
  acc[3][0] = fmaf((IV).w, (WV).x, acc[3][0]);               \
  acc[3][1] = fmaf((IV).w, (WV).y, acc[3][1]);               \
  acc[3][2] = fmaf((IV).w, (WV).z, acc[3][2]);               \
  acc[3][3] = fmaf((IV).w, (WV).w, acc[3][3]);

__global__ __launch_bounds__(NTHR, 2)
void snn_pipe(Params p) {
#pragma clang fp contract(off)
  const int tid = threadIdx.x;
  const int blk = blockIdx.x;
  const int L   = blk >> 6;          // 0,1,2 = layers; 3 = layer-4 group
  const int g   = blk & 63;
  const int B0  = g * ROWS;
  const int LW  = (L < 3) ? L : 2;   // safe W index

  const int w    = tid >> 6;
  const int l    = tid & 63;
  const int hp   = w & 3;
  const int qp   = w >> 2;
  const int hsel = l & 15;
  const int jsel = l >> 4;
  const int hb   = hp * 64 + hsel * 4;
  const int jb   = qp * 16 + jsel * 4;

  const int sid = tid & 255;
  const int jq  = tid >> 8;

  __shared__ __align__(16) float in_lds[HH * LSTR];
  __shared__ __align__(16) float s3_lds[ROWS * S3P];
  __shared__ float wred[8][6];
  __shared__ float scal[2];
  __shared__ float l4u[64], l4v[64], l4s[64], l4t[64],
                   l4acc[64], l4vn[64], l4vth[64];

  // ---- prologue 1: W -> [k][h] transposed rows ----
  {
    const int gtid = blk * NTHR + tid;
    if (gtid < 16384) {
      const int h = gtid & 255, kq = gtid >> 8;
      #pragma unroll
      for (int ll = 0; ll < 3; ++ll) {
        float4 wv = *reinterpret_cast<const float4*>(p.W[ll] + (size_t)h * 256 + kq * 4);
        float* dst = p.wt3 + (size_t)ll * WLAYER + (size_t)(kq * 4) * KSTR + h;
        dst[0 * KSTR] = wv.x; dst[1 * KSTR] = wv.y;
        dst[2 * KSTR] = wv.z; dst[3 * KSTR] = wv.w;
      }
    }
    if (p.use_xt) {
      for (int sid0 = gtid; sid0 < BB * SS; sid0 += NGRID * NTHR) {
        const float* src = p.x + (size_t)sid0 * TT;
        #pragma unroll 1
        for (int t = 0; t < TT; ++t)
          p.xT[(size_t)t * (BB * SS) + sid0] = src[t];
      }
    }
  }

  // ---- per-thread state (layer groups only) ----
  float u[4][4], v[4][4], tp[4][4];
  float bL[4] = {0.f, 0.f, 0.f, 0.f};
  unsigned smask = 0;
  if (L < 3) {
    #pragma unroll
    for (int jj = 0; jj < 4; ++jj) {
      size_t idx = (size_t)(B0 + jb + jj) * HH + hb;
      float4 uu = *reinterpret_cast<const float4*>(p.fu[LW] + idx);
      float4 vv = *reinterpret_cast<const float4*>(p.fv[LW] + idx);
      float4 ss = *reinterpret_cast<const float4*>(p.fs[LW] + idx);
      u[jj][0] = uu.x; u[jj][1] = uu.y; u[jj][2] = uu.z; u[jj][3] = uu.w;
      v[jj][0] = vv.x; v[jj][1] = vv.y; v[jj][2] = vv.z; v[jj][3] = vv.w;
      if (ss.x != 0.0f) smask |= 1u << (jj * 4 + 0);
      if (ss.y != 0.0f) smask |= 1u << (jj * 4 + 1);
      if (ss.z != 0.0f) smask |= 1u << (jj * 4 + 2);
      if (ss.w != 0.0f) smask |= 1u << (jj * 4 + 3);
      #pragma unroll
      for (int i = 0; i < 4; ++i) tp[jj][i] = 0.5f;
    }
    float4 bb4 = *reinterpret_cast<const float4*>(p.bs[LW] + hb);
    bL[0] = bb4.x; bL[1] = bb4.y; bL[2] = bb4.z; bL[3] = bb4.w;
  } else if (tid < 64) {
    size_t idx = (size_t)(B0 + (tid >> 1)) * AA + (tid & 1);
    l4u[tid] = p.f4u[idx]; l4v[tid] = p.f4v[idx]; l4s[tid] = p.f4s[idx];
    l4t[tid] = 0.5f; l4acc[tid] = 0.0f;
  }
  __syncthreads();

  // ---- one-time global init barrier ----
  if (tid == 0) {
    uadd(&p.flags[520]);
    while (uload_acq(&p.flags[520]) < (unsigned)NGRID) __builtin_amdgcn_s_sleep(2);
  }
  __syncthreads();

  const float* wbase = p.wt3 + (size_t)LW * WLAYER + hb;
  const uint8_t* sb_in = (L > 0) ? p.sbuf + (size_t)(L - 1) * 2 * BB * HH : nullptr;
  uint8_t* sb_out      = (L < 3) ? p.sbuf + (size_t)L * 2 * BB * HH : nullptr;

  #pragma unroll 1
  for (int t = 0; t < TT; ++t) {
    const int par = t & 1;

    if (L < 3) {
      // ===================== layer group (L0/L1/L2) =====================
      // ---- 1. stage input ----
      if (L == 0) {
        if (p.use_xt) {
          const float* base = p.xT + (size_t)t * (BB * SS) + (size_t)B0 * SS;
          #pragma unroll
          for (int iq = 0; iq < 4; ++iq) {
            const int j = jq * 16 + iq * 4;
            float4 vv = make_float4(base[(size_t)(j + 0) * SS + sid],
                                    base[(size_t)(j + 1) * SS + sid],
                                    base[(size_t)(j + 2) * SS + sid],
                                    base[(size_t)(j + 3) * SS + sid]);
            *reinterpret_cast<float4*>(&in_lds[sid * LSTR + j]) = vv;
          }
        } else {
          #pragma unroll
          for (int iq = 0; iq < 4; ++iq) {
            const int j = jq * 16 + iq * 4;
            float4 vv = make_float4(
                p.x[((size_t)(B0 + j + 0) * SS + sid) * TT + t],
                p.x[((size_t)(B0 + j + 1) * SS + sid) * TT + t],
                p.x[((size_t)(B0 + j + 2) * SS + sid) * TT + t],
                p.x[((size_t)(B0 + j + 3) * SS + sid) * TT + t]);
            *reinterpret_cast<float4*>(&in_lds[sid * LSTR + j]) = vv;
          }
        }
      } else {
        const int hop = L - 1;
        if (tid == 0) {
          while (uload_acq(&p.flags[hop * 64 + g]) < (unsigned)(t + 1))
            __builtin_amdgcn_s_sleep(2);
        }
        __syncthreads();
        const uint8_t* src = sb_in + (size_t)par * BB * HH;
        #pragma unroll
        for (int iq = 0; iq < 4; ++iq) {
          const int j = jq * 16 + iq * 4;
          float4 vv = make_float4(
              (float)bload(src + (size_t)(B0 + j + 0) * HH + sid),
              (float)bload(src + (size_t)(B0 + j + 1) * HH + sid),
              (float)bload(src + (size_t)(B0 + j + 2) * HH + sid),
              (float)bload(src + (size_t)(B0 + j + 3) * HH + sid));
          *reinterpret_cast<float4*>(&in_lds[sid * LSTR + j]) = vv;
        }
        __syncthreads();
        if (tid == 0) ustore_rel(&p.flags[256 + hop * 64 + g], (unsigned)(t + 1));
      }
      __syncthreads();

      // ---- 2. GEMM ----
      float acc[4][4];
      #pragma unroll
      for (int jj = 0; jj < 4; ++jj)
        #pragma unroll
        for (int i = 0; i < 4; ++i) acc[jj][i] = 0.0f;
      #pragma unroll 2
      for (int k4 = 0; k4 < 64; ++k4) {
        const float* wk = wbase + (size_t)(k4 * 4) * KSTR;
        float4 w0 = *reinterpret_cast<const float4*>(wk);
        float4 w1 = *reinterpret_cast<const float4*>(wk + KSTR);
        float4 w2 = *reinterpret_cast<const float4*>(wk + 2 * KSTR);
        float4 w3 = *reinterpret_cast<const float4*>(wk + 3 * KSTR);
        const float* ib = &in_lds[(k4 * 4) * LSTR + jb];
        float4 i0 = *reinterpret_cast<const float4*>(ib);
        float4 i1 = *reinterpret_cast<const float4*>(ib + LSTR);
        float4 i2 = *reinterpret_cast<const float4*>(ib + 2 * LSTR);
        float4 i3 = *reinterpret_cast<const float4*>(ib + 3 * LSTR);
        OUTER(i0, w0);
        OUTER(i1, w1);
        OUTER(i2, w2);
        OUTER(i3, w3);
      }

      // ---- 3. stats(t-1): poll own counter, parallel reduce ----
      if (t > 0) {
        if (tid == 0) {
          while (uload_acq(&p.flags[512 + L]) < (unsigned)(NLG * t))
            __builtin_amdgcn_s_sleep(2);
        }
        __syncthreads();
        if (w == 0) {
          const float* pb = p.partials + (size_t)(L * 2 + ((t - 1) & 1)) * 6 * 64;
          float r[6];
          #pragma unroll
          for (int st = 0; st < 6; ++st) {
            float rr = pload(pb + st * 64 + l);
            if (st == 0 || st == 3) {
              #pragma unroll
              for (int m = 1; m < 64; m <<= 1) rr += __shfl_xor(rr, m);
            } else if (st == 1 || st == 4) {
              #pragma unroll
              for (int m = 1; m < 64; m <<= 1) rr = fmaxf(rr, __shfl_xor(rr, m));
            } else {
              #pragma unroll
              for (int m = 1; m < 64; m <<= 1) rr = fminf(rr, __shfl_xor(rr, m));
            }
            r[st] = rr;
          }
          if (l == 0) {
            const float invN = 1.0f / 524288.0f;
            scal[0] = (r[0] * invN) - 0.2f * (r[1] - r[2]);
            scal[1] = (r[3] * invN) - 0.2f * (r[4] - r[5]);
          }
        }
        __syncthreads();
        const float Vm = scal[0], Vt = scal[1];
        #pragma unroll
        for (int jj = 0; jj < 4; ++jj)
          #pragma unroll
          for (int i = 0; i < 4; ++i) {
            float d = v[jj][i] - Vm;
            float sp = logf(1.0f + expf(d * 0.25f));
            tp[jj][i] = (0.01f * d + Vt) + sp;
          }
        __syncthreads();
      }

      // ---- 4. LIF + wave stats ----
      float sv = 0.f, svt = 0.f;
      float mxv = -3.402823466e38f, mnv = 3.402823466e38f;
      float mxvt = -3.402823466e38f, mnvt = 3.402823466e38f;
      unsigned nsmask = 0;
      #pragma unroll
      for (int jj = 0; jj < 4; ++jj) {
        #pragma unroll
        for (int i = 0; i < 4; ++i) {
          float un = fmaf(u[jj][i], 0.5f, acc[jj][i]) + bL[i];
          float vp = v[jj][i];
          float vd = ((smask >> (jj * 4 + i)) & 1u) ? 0.0f : vp * 0.75f;
          float vn = vd + un;
          float en = expf((vp - vn) / 3.0f) - 1.0f;
          float vt = 0.5f * tp[jj][i] + 0.5f * en;
          const bool sx = vn > vt;
          u[jj][i] = un; v[jj][i] = vn;
          if (sx) nsmask |= 1u << (jj * 4 + i);
          sv += vn; svt += vt;
          mxv = fmaxf(mxv, vn); mnv = fminf(mnv, vn);
          mxvt = fmaxf(mxvt, vt); mnvt = fminf(mnvt, vt);
        }
      }
      smask = nsmask;
      #pragma unroll
      for (int m = 1; m < 64; m <<= 1) {
        sv += __shfl_xor(sv, m);   svt += __shfl_xor(svt, m);
        mxv = fmaxf(mxv, __shfl_xor(mxv, m));  mnv = fminf(mnv, __shfl_xor(mnv, m));
        mxvt = fmaxf(mxvt, __shfl_xor(mxvt, m)); mnvt = fminf(mnvt, __shfl_xor(mnvt, m));
      }
      if ((tid & 63) == 0) {
        int wv = tid >> 6;
        wred[wv][0] = sv;  wred[wv][1] = mxv;  wred[wv][2] = mnv;
        wred[wv][3] = svt; wred[wv][4] = mxvt; wred[wv][5] = mnvt;
      }
      #pragma unroll
      for (int jj = 0; jj < 4; ++jj) {
        *reinterpret_cast<float4*>(&s3_lds[(jb + jj) * S3P + hb]) = make_float4(
            ((nsmask >> (jj * 4 + 0)) & 1u) ? 1.0f : 0.0f,
            ((nsmask >> (jj * 4 + 1)) & 1u) ? 1.0f : 0.0f,
            ((nsmask >> (jj * 4 + 2)) & 1u) ? 1.0f : 0.0f,
            ((nsmask >> (jj * 4 + 3)) & 1u) ? 1.0f : 0.0f);
      }
      __syncthreads();   // wred + s3_lds visible

      // ---- 5. partials, ack, early arrive, publish bytes, prod flag ----
      if (tid < 6) {
        const int st = tid;
        float r = wred[0][st];
        if (st == 0 || st == 3) {
          #pragma unroll
          for (int wv = 1; wv < 8; ++wv) r = r + wred[wv][st];
        } else if (st == 1 || st == 4) {
          #pragma unroll
          for (int wv = 1; wv < 8; ++wv) r = fmaxf(r, wred[wv][st]);
        } else {
          #pragma unroll
          for (int wv = 1; wv < 8; ++wv) r = fminf(r, wred[wv][st]);
        }
        pstore(p.partials + (size_t)(L * 2 + par) * 6 * 64 + st * 64 + g, r);
      }
      if (t >= 2 && tid == 1) {
        while (uload_acq(&p.flags[256 + L * 64 + g]) < (unsigned)(t - 1))
          __builtin_amdgcn_s_sleep(2);
      }
      __syncthreads();
      if (tid == 0) uadd(&p.flags[512 + L]);
      uint8_t* dst = sb_out + (size_t)par * BB * HH;
      #pragma unroll
      for (int jr = 0; jr < 16; ++jr) {
        const int j = jq * 16 + jr;
        bstore(dst + (size_t)(B0 + j) * HH + sid,
               (uint8_t)(s3_lds[j * S3P + sid] != 0.0f ? 1 : 0));
      }
      __syncthreads();
      if (tid == 0) ustore_rel(&p.flags[L * 64 + g], (unsigned)(t + 1));
    } else {
      // ===================== layer-4 group =====================
      // ---- 1. stage s3 bytes -> s3_lds ----
      if (tid == 0) {
        while (uload_acq(&p.flags[2 * 64 + g]) < (unsigned)(t + 1))
          __builtin_amdgcn_s_sleep(2);
      }
      __syncthreads();
      {
        const uint8_t* src = sb_in + (size_t)par * BB * HH;
        #pragma unroll
        for (int jr = 0; jr < 16; ++jr) {
          const int j = jq * 16 + jr;
          s3_lds[j * S3P + sid] = (float)bload(src + (size_t)(B0 + j) * HH + sid);
        }
      }
      __syncthreads();
      if (tid == 0) ustore_rel(&p.flags[256 + 2 * 64 + g], (unsigned)(t + 1));

      // ---- 2. stats(t-1) ch3 + temporal l4t ----
      if (t > 0) {
        if (tid == 0) {
          while (uload_acq(&p.flags[512 + 3]) < (unsigned)(NLG * t))
            __builtin_amdgcn_s_sleep(2);
        }
        __syncthreads();
        if (w == 0) {
          const float* pb = p.partials + (size_t)(3 * 2 + ((t - 1) & 1)) * 6 * 64;
          float r[6];
          #pragma unroll
          for (int st = 0; st < 6; ++st) {
            float rr = pload(pb + st * 64 + l);
            if (st == 0 || st == 3) {
              #pragma unroll
              for (int m = 1; m < 64; m <<= 1) rr += __shfl_xor(rr, m);
            } else if (st == 1 || st == 4) {
              #pragma unroll
              for (int m = 1; m < 64; m <<= 1) rr = fmaxf(rr, __shfl_xor(rr, m));
            } else {
              #pragma unroll
              for (int m = 1; m < 64; m <<= 1) rr = fminf(rr, __shfl_xor(rr, m));
            }
            r[st] = rr;
          }
          if (l == 0) {
            const float invN = 1.0f / 4096.0f;
            scal[0] = (r[0] * invN) - 0.2f * (r[1] - r[2]);
            scal[1] = (r[3] * invN) - 0.2f * (r[4] - r[5]);
          }
        }
        __syncthreads();
        if (tid < 64) {
          const float Vm = scal[0], Vt = scal[1];
          float d = l4v[tid] - Vm;
          float sp = logf(1.0f + expf(d * 0.25f));
          l4t[tid] = (0.01f * d + Vt) + sp;
        }
        __syncthreads();
      }

      // ---- 3. layer-4 compute (same tree as R16) ----
      {
        const int d = tid >> 3, c = tid & 7;
        const int j4 = d >> 1, a4 = d & 1;
        float part = 0.0f;
        #pragma unroll
        for (int i = 0; i < 32; ++i) {
          int k = c + 8 * i;
          part = fmaf(s3_lds[j4 * S3P + k], p.W4[a4 * HH + k], part);
        }
        #pragma unroll
        for (int m = 1; m < 8; m <<= 1) part += __shfl_xor(part, m);
        if (c == 0) {
          float un = fmaf(l4u[d], 0.5f, part) + p.b4[a4];
          float vp = l4v[d];
          float vd = (vp * 0.75f) * (1.0f - l4s[d]);
          float vn = vd + un;
          float en = expf((vp - vn) / 3.0f) - 1.0f;
          float vt = 0.5f * l4t[d] + 0.5f * en;
          float sx = (vn > vt) ? 1.0f : 0.0f;
          l4u[d] = un; l4v[d] = vn; l4s[d] = sx;
          l4acc[d] += sx; l4vn[d] = vn; l4vth[d] = vt;
        }
      }
      __syncthreads();

      // ---- 4. ch3 partials + arrive ----
      if (tid < 64) {
        float a = l4vn[tid], b = l4vth[tid];
        float s4 = a, mx4 = a, mn4 = a;
        float st4 = b, mxt4 = b, mnt4 = b;
        #pragma unroll
        for (int m = 1; m < 64; m <<= 1) {
          s4  += __shfl_xor(s4, m);   st4 += __shfl_xor(st4, m);
          mx4  = fmaxf(mx4,  __shfl_xor(mx4, m));  mn4  = fminf(mn4,  __shfl_xor(mn4, m));
          mxt4 = fmaxf(mxt4, __shfl_xor(mxt4, m)); mnt4 = fminf(mnt4, __shfl_xor(mnt4, m));
        }
        if (tid == 0) {
          float* pp = p.partials + (size_t)(3 * 2 + par) * 6 * 64 + g;
          pstore(pp + 0 * 64, s4);   pstore(pp + 1 * 64, mx4);  pstore(pp + 2 * 64, mn4);
          pstore(pp + 3 * 64, st4);  pstore(pp + 4 * 64, mxt4); pstore(pp + 5 * 64, mnt4);
        }
      }
      __syncthreads();
      if (tid == 0) uadd(&p.flags[512 + 3]);
    }
  }

  if (L == 3 && tid < 64)
    p.out[(size_t)(B0 + (tid >> 1)) * AA + (tid & 1)] = l4acc[tid] / 50.0f;
}

extern "C" void kernel_launch(void* const* d_in, const int* in_sizes, int n_in,
                              void* d_out, int out_size, void* d_ws, size_t ws_size,
                              hipStream_t stream) {
  Params p;
  p.x     = (const float*)d_in[0];
  p.fu[0] = (const float*)d_in[1];  p.fv[0] = (const float*)d_in[2];  p.fs[0] = (const float*)d_in[3];
  p.fu[1] = (const float*)d_in[4];  p.fv[1] = (const float*)d_in[5];  p.fs[1] = (const float*)d_in[6];
  p.fu[2] = (const float*)d_in[7];  p.fv[2] = (const float*)d_in[8];  p.fs[2] = (const float*)d_in[9];
  p.f4u   = (const float*)d_in[10]; p.f4v   = (const float*)d_in[11]; p.f4s   = (const float*)d_in[12];
  p.W[0]  = (const float*)d_in[13]; p.bs[0] = (const float*)d_in[14];
  p.W[1]  = (const float*)d_in[15]; p.bs[1] = (const float*)d_in[16];
  p.W[2]  = (const float*)d_in[17]; p.bs[2] = (const float*)d_in[18];
  p.W4    = (const float*)d_in[19]; p.b4    = (const float*)d_in[20];
  p.out   = (float*)d_out;

  float* ws   = (float*)d_ws;
  p.wt3       = ws;                           // 3*69632 = 208896 floats
  p.partials  = ws + 208896;                  // 3072 floats
  p.flags     = (unsigned*)(ws + 211968);     // 1024 uints
  p.sbuf      = (uint8_t*)(ws + 212992);      // 3*2*2048*256 B = 786432 floats
  p.xT        = ws + 409600;                  // 50*524288 floats
  size_t need = ((size_t)409600 + (size_t)TT * BB * SS) * sizeof(float);
  p.use_xt    = (ws_size >= need) ? 1 : 0;

  hipMemsetAsync((void*)p.flags, 0, 4096, stream);
  snn_pipe<<<dim3(NGRID), dim3(NTHR), 0, stream>>>(p);
}

// Round 20
// 1871.396 us; speedup vs baseline: 1.1488x; 1.1488x over previous
//
#include <hip/hip_runtime.h>
#include <cstdint>
#include <cstddef>

// Problem dims (fixed)
#define BB 2048
#define SS 256
#define HH 256
#define AA 2
#define TT 50
// Pipeline: 3 layer-groups x 64 blocks, 32 rows/block, 512 thr (8 waves)
#define ROWS  32
#define NTHR  512
#define NLG   64
#define NGRID 192
#define KSTR  272            // wt: floats per k row (256 + 16 pad)
#define WLAYER (256 * KSTR)
#define LSTR  36             // in_lds row stride: 32 j + 4 pad
#define S3P   260            // s3_lds row stride (multiple of 4)

struct Params {
  const float* x;
  const float* fu[3]; const float* fv[3]; const float* fs[3];
  const float* f4u; const float* f4v; const float* f4s;
  const float* W[3]; const float* bs[3];
  const float* W4; const float* b4;
  float* out;
  float* wt3;        // [3][256 k][272] W transposed
  float* partials;   // [4 ch][2 par][6 st][64 g]
  unsigned* flags;   // [0..127] prod[hop][g], [128..255] ack[hop][g],
                     // [256..258] ctr[L], [260] init
  uint8_t* sbuf;     // [2 hop][2 par][2048][256] spike bytes
  float* xT;         // [TT][BB*SS] (optional)
  int use_xt;
};

__device__ __forceinline__ void pstore(float* p, float v) {
  __hip_atomic_store(p, v, __ATOMIC_RELAXED, __HIP_MEMORY_SCOPE_AGENT);
}
__device__ __forceinline__ float pload(const float* p) {
  return __hip_atomic_load(p, __ATOMIC_RELAXED, __HIP_MEMORY_SCOPE_AGENT);
}
__device__ __forceinline__ void bstore(uint8_t* p, uint8_t v) {
  __hip_atomic_store(p, v, __ATOMIC_RELAXED, __HIP_MEMORY_SCOPE_AGENT);
}
__device__ __forceinline__ uint8_t bload(const uint8_t* p) {
  return __hip_atomic_load(p, __ATOMIC_RELAXED, __HIP_MEMORY_SCOPE_AGENT);
}
__device__ __forceinline__ unsigned uload_acq(const unsigned* p) {
  return __hip_atomic_load(p, __ATOMIC_ACQUIRE, __HIP_MEMORY_SCOPE_AGENT);
}
__device__ __forceinline__ void ustore_rel(unsigned* p, unsigned v) {
  __hip_atomic_store(p, v, __ATOMIC_RELEASE, __HIP_MEMORY_SCOPE_AGENT);
}
__device__ __forceinline__ void uadd(unsigned* p) {
  __hip_atomic_fetch_add(p, 1u, __ATOMIC_ACQ_REL, __HIP_MEMORY_SCOPE_AGENT);
}

// 16 FMAs: acc[jj][i] += IV[jj] * WV[i]
#define OUTER(IV, WV)                                        \
  acc[0][0] = fmaf((IV).x, (WV).x, acc[0][0]);               \
  acc[0][1] = fmaf((IV).x, (WV).y, acc[0][1]);               \
  acc[0][2] = fmaf((IV).x, (WV).z, acc[0][2]);               \
  acc[0][3] = fmaf((IV).x, (WV).w, acc[0][3]);               \
  acc[1][0] = fmaf((IV).y, (WV).x, acc[1][0]);               \
  acc[1][1] = fmaf((IV).y, (WV).y, acc[1][1]);               \
  acc[1][2] = fmaf((IV).y, (WV).z, acc[1][2]);               \
  acc[1][3] = fmaf((IV).y, (WV).w, acc[1][3]);               \
  acc[2][0] = fmaf((IV).z, (WV).x, acc[2][0]);               \
  acc[2][1] = fmaf((IV).z, (WV).y, acc[2][1]);               \
  acc[2][2] = fmaf((IV).z, (WV).z, acc[2][2]);               \
  acc[2][3] = fmaf((IV).z, (WV).w, acc[2][3]);               \
  acc[3][0] = fmaf((IV).w, (WV).x, acc[3][0]);               \
  acc[3][1] = fmaf((IV).w, (WV).y, acc[3][1]);               \
  acc[3][2] = fmaf((IV).w, (WV).z, acc[3][2]);               \
  acc[3][3] = fmaf((IV).w, (WV).w, acc[3][3]);

__global__ __launch_bounds__(NTHR, 2)
void snn_pipe(Params p) {
#pragma clang fp contract(off)
  const int tid = threadIdx.x;
  const int blk = blockIdx.x;
  const int L   = blk >> 6;          // 0,1,2 (group 2 also does layer 4)
  const int g   = blk & 63;
  const int B0  = g * ROWS;

  const int w    = tid >> 6;
  const int l    = tid & 63;
  const int hp   = w & 3;
  const int qp   = w >> 2;
  const int hsel = l & 15;
  const int jsel = l >> 4;
  const int hb   = hp * 64 + hsel * 4;
  const int jb   = qp * 16 + jsel * 4;

  const int sid = tid & 255;
  const int jq  = tid >> 8;

  __shared__ __align__(16) float in_lds[HH * LSTR];
  __shared__ __align__(16) float s3_lds[ROWS * S3P];
  __shared__ float wred[8][6];
  __shared__ float scal[2][2];
  __shared__ float l4u[64], l4v[64], l4s[64], l4t[64],
                   l4acc[64], l4vn[64], l4vth[64];

  // ---- prologue 1: W -> [k][h] transposed rows ----
  {
    const int gtid = blk * NTHR + tid;
    if (gtid < 16384) {
      const int h = gtid & 255, kq = gtid >> 8;
      #pragma unroll
      for (int ll = 0; ll < 3; ++ll) {
        float4 wv = *reinterpret_cast<const float4*>(p.W[ll] + (size_t)h * 256 + kq * 4);
        float* dst = p.wt3 + (size_t)ll * WLAYER + (size_t)(kq * 4) * KSTR + h;
        dst[0 * KSTR] = wv.x; dst[1 * KSTR] = wv.y;
        dst[2 * KSTR] = wv.z; dst[3 * KSTR] = wv.w;
      }
    }
    // ---- prologue 2: transpose x -> xT ----
    if (p.use_xt) {
      for (int sid0 = gtid; sid0 < BB * SS; sid0 += NGRID * NTHR) {
        const float* src = p.x + (size_t)sid0 * TT;
        #pragma unroll 1
        for (int t = 0; t < TT; ++t)
          p.xT[(size_t)t * (BB * SS) + sid0] = src[t];
      }
    }
  }

  // ---- per-thread state ----
  float u[4][4], v[4][4], tp[4][4];
  unsigned smask = 0;
  #pragma unroll
  for (int jj = 0; jj < 4; ++jj) {
    size_t idx = (size_t)(B0 + jb + jj) * HH + hb;
    float4 uu = *reinterpret_cast<const float4*>(p.fu[L] + idx);
    float4 vv = *reinterpret_cast<const float4*>(p.fv[L] + idx);
    float4 ss = *reinterpret_cast<const float4*>(p.fs[L] + idx);
    u[jj][0] = uu.x; u[jj][1] = uu.y; u[jj][2] = uu.z; u[jj][3] = uu.w;
    v[jj][0] = vv.x; v[jj][1] = vv.y; v[jj][2] = vv.z; v[jj][3] = vv.w;
    if (ss.x != 0.0f) smask |= 1u << (jj * 4 + 0);
    if (ss.y != 0.0f) smask |= 1u << (jj * 4 + 1);
    if (ss.z != 0.0f) smask |= 1u << (jj * 4 + 2);
    if (ss.w != 0.0f) smask |= 1u << (jj * 4 + 3);
    #pragma unroll
    for (int i = 0; i < 4; ++i) tp[jj][i] = 0.5f;
  }
  const float4 bb4 = *reinterpret_cast<const float4*>(p.bs[L] + hb);
  const float bL[4] = { bb4.x, bb4.y, bb4.z, bb4.w };
  if (L == 2 && tid < 64) {
    size_t idx = (size_t)(B0 + (tid >> 1)) * AA + (tid & 1);
    l4u[tid] = p.f4u[idx]; l4v[tid] = p.f4v[idx]; l4s[tid] = p.f4s[idx];
    l4t[tid] = 0.5f; l4acc[tid] = 0.0f;
  }
  __syncthreads();

  // ---- one-time global init barrier ----
  if (tid == 0) {
    uadd(&p.flags[260]);
    while (uload_acq(&p.flags[260]) < (unsigned)NGRID) __builtin_amdgcn_s_sleep(2);
  }
  __syncthreads();

  const float* wbase = p.wt3 + (size_t)L * WLAYER + hb;
  const uint8_t* sb_in = (L > 0) ? p.sbuf + (size_t)(L - 1) * 2 * BB * HH : nullptr;
  uint8_t* sb_out      = (L < 2) ? p.sbuf + (size_t)L * 2 * BB * HH : nullptr;

  #pragma unroll 1
  for (int t = 0; t < TT; ++t) {
    const int par = t & 1;
    // ---- 1. stage input [k][j] into in_lds ----
    if (L == 0) {
      if (p.use_xt) {
        const float* base = p.xT + (size_t)t * (BB * SS) + (size_t)B0 * SS;
        #pragma unroll
        for (int iq = 0; iq < 4; ++iq) {
          const int j = jq * 16 + iq * 4;
          float4 vv = make_float4(base[(size_t)(j + 0) * SS + sid],
                                  base[(size_t)(j + 1) * SS + sid],
                                  base[(size_t)(j + 2) * SS + sid],
                                  base[(size_t)(j + 3) * SS + sid]);
          *reinterpret_cast<float4*>(&in_lds[sid * LSTR + j]) = vv;
        }
      } else {
        #pragma unroll
        for (int iq = 0; iq < 4; ++iq) {
          const int j = jq * 16 + iq * 4;
          float4 vv = make_float4(
              p.x[((size_t)(B0 + j + 0) * SS + sid) * TT + t],
              p.x[((size_t)(B0 + j + 1) * SS + sid) * TT + t],
              p.x[((size_t)(B0 + j + 2) * SS + sid) * TT + t],
              p.x[((size_t)(B0 + j + 3) * SS + sid) * TT + t]);
          *reinterpret_cast<float4*>(&in_lds[sid * LSTR + j]) = vv;
        }
      }
    } else {
      const int hop = L - 1;
      if (tid == 0) {
        while (uload_acq(&p.flags[hop * 64 + g]) < (unsigned)(t + 1))
          __builtin_amdgcn_s_sleep(2);
      }
      __syncthreads();
      const uint8_t* src = sb_in + (size_t)par * BB * HH;
      #pragma unroll
      for (int iq = 0; iq < 4; ++iq) {
        const int j = jq * 16 + iq * 4;
        float4 vv = make_float4(
            (float)bload(src + (size_t)(B0 + j + 0) * HH + sid),
            (float)bload(src + (size_t)(B0 + j + 1) * HH + sid),
            (float)bload(src + (size_t)(B0 + j + 2) * HH + sid),
            (float)bload(src + (size_t)(B0 + j + 3) * HH + sid));
        *reinterpret_cast<float4*>(&in_lds[sid * LSTR + j]) = vv;
      }
      __syncthreads();   // staging reads done
      if (tid == 0) ustore_rel(&p.flags[128 + hop * 64 + g], (unsigned)(t + 1));
    }
    __syncthreads();     // in_lds ready

    // ---- 2. GEMM ----
    float acc[4][4];
    #pragma unroll
    for (int jj = 0; jj < 4; ++jj)
      #pragma unroll
      for (int i = 0; i < 4; ++i) acc[jj][i] = 0.0f;
    #pragma unroll 2
    for (int k4 = 0; k4 < 64; ++k4) {
      const float* wk = wbase + (size_t)(k4 * 4) * KSTR;
      float4 w0 = *reinterpret_cast<const float4*>(wk);
      float4 w1 = *reinterpret_cast<const float4*>(wk + KSTR);
      float4 w2 = *reinterpret_cast<const float4*>(wk + 2 * KSTR);
      float4 w3 = *reinterpret_cast<const float4*>(wk + 3 * KSTR);
      const float* ib = &in_lds[(k4 * 4) * LSTR + jb];
      float4 i0 = *reinterpret_cast<const float4*>(ib);
      float4 i1 = *reinterpret_cast<const float4*>(ib + LSTR);
      float4 i2 = *reinterpret_cast<const float4*>(ib + 2 * LSTR);
      float4 i3 = *reinterpret_cast<const float4*>(ib + 3 * LSTR);
      OUTER(i0, w0);
      OUTER(i1, w1);
      OUTER(i2, w2);
      OUTER(i3, w3);
    }

    // ---- 3. stats(t-1): group sync, parallel reduce (R16 shape) ----
    if (t > 0) {
      if (tid == 0) {
        while (uload_acq(&p.flags[256 + L]) < (unsigned)(NLG * t))
          __builtin_amdgcn_s_sleep(2);
      }
      __syncthreads();
      {
        const int wv = tid >> 6, ln = tid & 63;
        if (wv == 0 || (wv == 1 && L == 2)) {
          const int ch = (wv == 0) ? L : 3;
          const float* pb = p.partials + (size_t)(ch * 2 + ((t - 1) & 1)) * 6 * 64;
          float r[6];
          #pragma unroll
          for (int st = 0; st < 6; ++st) {
            float rr = pload(pb + st * 64 + ln);
            if (st == 0 || st == 3) {
              #pragma unroll
              for (int m = 1; m < 64; m <<= 1) rr += __shfl_xor(rr, m);
            } else if (st == 1 || st == 4) {
              #pragma unroll
              for (int m = 1; m < 64; m <<= 1) rr = fmaxf(rr, __shfl_xor(rr, m));
            } else {
              #pragma unroll
              for (int m = 1; m < 64; m <<= 1) rr = fminf(rr, __shfl_xor(rr, m));
            }
            r[st] = rr;
          }
          if (ln == 0) {
            const float invN = (ch == 3) ? (1.0f / 4096.0f) : (1.0f / 524288.0f);
            scal[wv][0] = (r[0] * invN) - 0.2f * (r[1] - r[2]);
            scal[wv][1] = (r[3] * invN) - 0.2f * (r[4] - r[5]);
          }
        }
      }
      __syncthreads();
      {
        const float Vm = scal[0][0], Vt = scal[0][1];
        #pragma unroll
        for (int jj = 0; jj < 4; ++jj)
          #pragma unroll
          for (int i = 0; i < 4; ++i) {
            float d = v[jj][i] - Vm;            // v holds v(t-1)
            float sp = logf(1.0f + expf(d * 0.25f));
            tp[jj][i] = (0.01f * d + Vt) + sp;
          }
      }
      if (L == 2 && tid < 64) {
        const float Vm = scal[1][0], Vt = scal[1][1];
        float d = l4v[tid] - Vm;
        float sp = logf(1.0f + expf(d * 0.25f));
        l4t[tid] = (0.01f * d + Vt) + sp;
      }
      __syncthreads();
    }

    // ---- 4. LIF + wave stats ----
    float sv = 0.f, svt = 0.f;
    float mxv = -3.402823466e38f, mnv = 3.402823466e38f;
    float mxvt = -3.402823466e38f, mnvt = 3.402823466e38f;
    unsigned nsmask = 0;
    #pragma unroll
    for (int jj = 0; jj < 4; ++jj) {
      #pragma unroll
      for (int i = 0; i < 4; ++i) {
        float un = fmaf(u[jj][i], 0.5f, acc[jj][i]) + bL[i];
        float vp = v[jj][i];
        float vd = ((smask >> (jj * 4 + i)) & 1u) ? 0.0f : vp * 0.75f;
        float vn = vd + un;
        float en = expf((vp - vn) / 3.0f) - 1.0f;
        float vt = 0.5f * tp[jj][i] + 0.5f * en;
        const bool sx = vn > vt;
        u[jj][i] = un; v[jj][i] = vn;
        if (sx) nsmask |= 1u << (jj * 4 + i);
        sv += vn; svt += vt;
        mxv = fmaxf(mxv, vn); mnv = fminf(mnv, vn);
        mxvt = fmaxf(mxvt, vt); mnvt = fminf(mnvt, vt);
      }
    }
    smask = nsmask;
    #pragma unroll
    for (int m = 1; m < 64; m <<= 1) {
      sv += __shfl_xor(sv, m);   svt += __shfl_xor(svt, m);
      mxv = fmaxf(mxv, __shfl_xor(mxv, m));  mnv = fminf(mnv, __shfl_xor(mnv, m));
      mxvt = fmaxf(mxvt, __shfl_xor(mxvt, m)); mnvt = fminf(mnvt, __shfl_xor(mnvt, m));
    }
    if ((tid & 63) == 0) {
      int wv = tid >> 6;
      wred[wv][0] = sv;  wred[wv][1] = mxv;  wred[wv][2] = mnv;
      wred[wv][3] = svt; wred[wv][4] = mxvt; wred[wv][5] = mnvt;
    }
    #pragma unroll
    for (int jj = 0; jj < 4; ++jj) {
      *reinterpret_cast<float4*>(&s3_lds[(jb + jj) * S3P + hb]) = make_float4(
          ((nsmask >> (jj * 4 + 0)) & 1u) ? 1.0f : 0.0f,
          ((nsmask >> (jj * 4 + 1)) & 1u) ? 1.0f : 0.0f,
          ((nsmask >> (jj * 4 + 2)) & 1u) ? 1.0f : 0.0f,
          ((nsmask >> (jj * 4 + 3)) & 1u) ? 1.0f : 0.0f);
    }
    __syncthreads();   // wred + s3_lds visible

    if (L < 2) {
      // ---- 5a. partials(chL), ack, early arrive, byte publish ----
      if (tid < 6) {
        const int st = tid;
        float r = wred[0][st];
        if (st == 0 || st == 3) {
          #pragma unroll
          for (int wv = 1; wv < 8; ++wv) r = r + wred[wv][st];
        } else if (st == 1 || st == 4) {
          #pragma unroll
          for (int wv = 1; wv < 8; ++wv) r = fmaxf(r, wred[wv][st]);
        } else {
          #pragma unroll
          for (int wv = 1; wv < 8; ++wv) r = fminf(r, wred[wv][st]);
        }
        pstore(p.partials + (size_t)(L * 2 + par) * 6 * 64 + st * 64 + g, r);
      }
      if (t >= 2 && tid == 1) {
        while (uload_acq(&p.flags[128 + L * 64 + g]) < (unsigned)(t - 1))
          __builtin_amdgcn_s_sleep(2);
      }
      __syncthreads();                // partials stored + ack ok
      if (tid == 0) uadd(&p.flags[256 + L]);   // arrive stats counter EARLY
      uint8_t* dst = sb_out + (size_t)par * BB * HH;
      #pragma unroll
      for (int jr = 0; jr < 16; ++jr) {
        const int j = jq * 16 + jr;
        bstore(dst + (size_t)(B0 + j) * HH + sid,
               (uint8_t)(s3_lds[j * S3P + sid] != 0.0f ? 1 : 0));
      }
      __syncthreads();                // publish stores issued
      if (tid == 0) ustore_rel(&p.flags[L * 64 + g], (unsigned)(t + 1));
    } else {
      // ---- 5b. L2: partials(ch2); layer 4; ch3; arrive ----
      if (tid < 6) {
        const int st = tid;
        float r = wred[0][st];
        if (st == 0 || st == 3) {
          #pragma unroll
          for (int wv = 1; wv < 8; ++wv) r = r + wred[wv][st];
        } else if (st == 1 || st == 4) {
          #pragma unroll
          for (int wv = 1; wv < 8; ++wv) r = fmaxf(r, wred[wv][st]);
        } else {
          #pragma unroll
          for (int wv = 1; wv < 8; ++wv) r = fminf(r, wred[wv][st]);
        }
        pstore(p.partials + (size_t)(2 * 2 + par) * 6 * 64 + st * 64 + g, r);
      }
      __syncthreads();   // ch2 partials stored (s3 already visible)

      {
        const int d = tid >> 3, c = tid & 7;
        const int j4 = d >> 1, a4 = d & 1;
        float part = 0.0f;
        #pragma unroll
        for (int i = 0; i < 32; ++i) {
          int k = c + 8 * i;
          part = fmaf(s3_lds[j4 * S3P + k], p.W4[a4 * HH + k], part);
        }
        #pragma unroll
        for (int m = 1; m < 8; m <<= 1) part += __shfl_xor(part, m);
        if (c == 0) {
          float un = fmaf(l4u[d], 0.5f, part) + p.b4[a4];
          float vp = l4v[d];
          float vd = (vp * 0.75f) * (1.0f - l4s[d]);
          float vn = vd + un;
          float en = expf((vp - vn) / 3.0f) - 1.0f;
          float vt = 0.5f * l4t[d] + 0.5f * en;
          float sx = (vn > vt) ? 1.0f : 0.0f;
          l4u[d] = un; l4v[d] = vn; l4s[d] = sx;
          l4acc[d] += sx; l4vn[d] = vn; l4vth[d] = vt;
        }
      }
      __syncthreads();   // l4vn/l4vth visible

      if (tid < 64) {    // parallel 64-lane reduction
        float a = l4vn[tid], b = l4vth[tid];
        float s4 = a, mx4 = a, mn4 = a;
        float st4 = b, mxt4 = b, mnt4 = b;
        #pragma unroll
        for (int m = 1; m < 64; m <<= 1) {
          s4  += __shfl_xor(s4, m);   st4 += __shfl_xor(st4, m);
          mx4  = fmaxf(mx4,  __shfl_xor(mx4, m));  mn4  = fminf(mn4,  __shfl_xor(mn4, m));
          mxt4 = fmaxf(mxt4, __shfl_xor(mxt4, m)); mnt4 = fminf(mnt4, __shfl_xor(mnt4, m));
        }
        if (tid == 0) {
          float* pp = p.partials + (size_t)(3 * 2 + par) * 6 * 64 + g;
          pstore(pp + 0 * 64, s4);   pstore(pp + 1 * 64, mx4);  pstore(pp + 2 * 64, mn4);
          pstore(pp + 3 * 64, st4);  pstore(pp + 4 * 64, mxt4); pstore(pp + 5 * 64, mnt4);
        }
      }
      __syncthreads();   // ch3 partials stored
      if (tid == 0) uadd(&p.flags[256 + L]);
    }
  }

  if (L == 2 && tid < 64)
    p.out[(size_t)(B0 + (tid >> 1)) * AA + (tid & 1)] = l4acc[tid] / 50.0f;
}

extern "C" void kernel_launch(void* const* d_in, const int* in_sizes, int n_in,
                              void* d_out, int out_size, void* d_ws, size_t ws_size,
                              hipStream_t stream) {
  Params p;
  p.x     = (const float*)d_in[0];
  p.fu[0] = (const float*)d_in[1];  p.fv[0] = (const float*)d_in[2];  p.fs[0] = (const float*)d_in[3];
  p.fu[1] = (const float*)d_in[4];  p.fv[1] = (const float*)d_in[5];  p.fs[1] = (const float*)d_in[6];
  p.fu[2] = (const float*)d_in[7];  p.fv[2] = (const float*)d_in[8];  p.fs[2] = (const float*)d_in[9];
  p.f4u   = (const float*)d_in[10]; p.f4v   = (const float*)d_in[11]; p.f4s   = (const float*)d_in[12];
  p.W[0]  = (const float*)d_in[13]; p.bs[0] = (const float*)d_in[14];
  p.W[1]  = (const float*)d_in[15]; p.bs[1] = (const float*)d_in[16];
  p.W[2]  = (const float*)d_in[17]; p.bs[2] = (const float*)d_in[18];
  p.W4    = (const float*)d_in[19]; p.b4    = (const float*)d_in[20];
  p.out   = (float*)d_out;

  float* ws   = (float*)d_ws;
  p.wt3       = ws;                           // 3*69632 = 208896 floats
  p.partials  = ws + 208896;                  // 3072 floats
  p.flags     = (unsigned*)(ws + 211968);     // 1024 uints
  p.sbuf      = (uint8_t*)(ws + 212992);      // 2*2*2048*256 B = 524288 floats
  p.xT        = ws + 737280;                  // 50*524288 floats
  size_t need = ((size_t)737280 + (size_t)TT * BB * SS) * sizeof(float);
  p.use_xt    = (ws_size >= need) ? 1 : 0;

  hipMemsetAsync((void*)p.flags, 0, 4096, stream);
  snn_pipe<<<dim3(NGRID), dim3(NTHR), 0, stream>>>(p);
}